// Round 12
// baseline (165.837 us; speedup 1.0000x reference)
//
#include <hip/hip_runtime.h>
#include <stdint.h>

// MHA fused: qkv = x @ w_qkv ; attention ; out [b,s,E] fp32
// Round 12: attn occupancy attack — QBLK=64, 4 waves = 2 q-halves x 2 key
// parities (in-block kv-split; exp partials additive, combined via LDS).
// Grid 1024 blocks -> 4 blocks/CU, 16 waves/CU. Per-wave tile body identical
// to verified round-11. GEMM: round-5 structure + bn-grouped XCD swizzle.

typedef __attribute__((ext_vector_type(8))) short v8s;     // 8 x bf16
typedef __attribute__((ext_vector_type(4))) float v4f;     // 16x16 accum
typedef __attribute__((ext_vector_type(16))) float f32x16; // 32x32 accum

__device__ __forceinline__ unsigned short bf16bits(float f) {
  union { float f; unsigned int u; } c; c.f = f;
  unsigned int u = c.u;
  unsigned int r = (u + 0x7fffu + ((u >> 16) & 1u)) >> 16;  // RNE
  return (unsigned short)r;
}

__device__ __forceinline__ v4f mfma16(v8s a, v8s b, v4f c) {
  return __builtin_amdgcn_mfma_f32_16x16x32_bf16(a, b, c, 0, 0, 0);
}
__device__ __forceinline__ f32x16 mfma32(v8s a, v8s b, f32x16 c) {
  return __builtin_amdgcn_mfma_f32_32x32x16_bf16(a, b, c, 0, 0, 0);
}
__device__ __forceinline__ f32x16 zero16() {
  f32x16 z;
#pragma unroll
  for (int i = 0; i < 16; ++i) z[i] = 0.f;
  return z;
}
__device__ __forceinline__ unsigned int cvtpk(float lo, float hi) {
  unsigned int r;
  asm("v_cvt_pk_bf16_f32 %0, %1, %2" : "=v"(r) : "v"(lo), "v"(hi));
  return r;
}
__device__ __forceinline__ void pl32swap(unsigned int& a, unsigned int& b) {
  asm volatile("v_permlane32_swap_b32 %0, %1" : "+v"(a), "+v"(b));
}

// async global->LDS, 16B per lane; lds dest must be wave-uniform base.
#define GLD16(g, l) __builtin_amdgcn_global_load_lds( \
    (const __attribute__((address_space(1))) unsigned int*)(g), \
    (__attribute__((address_space(3))) unsigned int*)(l), 16, 0, 0)

// ---------------- prep: x fp32 -> bf16 ----------------
__global__ __launch_bounds__(256) void cvt_x_kernel(const float4* __restrict__ x4,
                                                    ushort4* __restrict__ o4, int n4) {
  int i = blockIdx.x * 256 + threadIdx.x;
  if (i < n4) {
    float4 v = x4[i];
    ushort4 o;
    o.x = bf16bits(v.x); o.y = bf16bits(v.y); o.z = bf16bits(v.z); o.w = bf16bits(v.w);
    o4[i] = o;
  }
}

// ---------------- prep: w [1024][3072] f32 -> wT [3072][1024] bf16 ----------------
__global__ __launch_bounds__(256) void cvt_wT_kernel(const float* __restrict__ w,
                                                     unsigned short* __restrict__ wt) {
  __shared__ float t[32][33];
  int n0 = blockIdx.x * 32, k0 = blockIdx.y * 32;
  int tx = threadIdx.x & 31, ty = threadIdx.x >> 5;  // 32 x 8
  for (int i = 0; i < 4; ++i) {
    int kr = ty + i * 8;
    t[kr][tx] = w[(k0 + kr) * 3072 + n0 + tx];
  }
  __syncthreads();
  for (int i = 0; i < 4; ++i) {
    int nr = ty + i * 8;
    wt[(n0 + nr) * 1024 + k0 + tx] = bf16bits(t[tx][nr]);
  }
}

// ---------------- QKV GEMM (round-5 structure + bn-grouped XCD swizzle) ----------------
// Tile 64x128, BK=64, 4 waves 2x2 (wave 32x64), dbuf LDS, 1 barrier/iter.
// XCD swizzle: bn%8 == XCD -> each XCD's 3 B-panels (768KB) stay L2-resident.
// Q cols (bn<8) pre-scaled by log2(e)/32 so attn uses exp2 directly.
__global__ __launch_bounds__(256) void qkv_gemm(const unsigned short* __restrict__ A,
                                                const unsigned short* __restrict__ Bm,
                                                unsigned short* __restrict__ Cq,
                                                unsigned short* __restrict__ VTh) {
  __shared__ __align__(16) unsigned short S[24576];   // 48 KB
  int tid = threadIdx.x, lane = tid & 63, wave = tid >> 6;
  int wr = wave >> 1, wc = wave & 1;
  int flat = blockIdx.x + blockIdx.y * 64;            // grid (64,24) -> 0..1535
  int x = flat & 7, k = flat >> 3;                    // bijective: 1536 = 8*192
  int bm = k & 63, bn = (k >> 6) * 8 + x;             // XCD x owns bn%8==x

  v4f acc[2][4];
  for (int i = 0; i < 2; ++i)
    for (int j = 0; j < 4; ++j) acc[i][j] = (v4f){0.f, 0.f, 0.f, 0.f};

  auto STAGE = [&](int hh, int kk) {
    unsigned short* As = S + hh * 12288;
    unsigned short* Bs = As + 4096;
    for (int i = 0; i < 2; ++i) {
      int e = i * 256 + tid;
      int row = e >> 3, cc = e & 7;
      int sc = cc ^ (row & 7);
      GLD16(A + (bm * 64 + row) * 1024 + kk + sc * 8,
            (char*)As + (i * 256 + wave * 64) * 16);
    }
    for (int i = 0; i < 4; ++i) {
      int e = i * 256 + tid;
      int row = e >> 3, cc = e & 7;
      int sc = cc ^ (row & 7);
      GLD16(Bm + (bn * 128 + row) * 1024 + kk + sc * 8,
            (char*)Bs + (i * 256 + wave * 64) * 16);
    }
  };
  auto COMPUTE = [&](int hh) {
    const unsigned short* As = S + hh * 12288;
    const unsigned short* Bs = As + 4096;
    for (int ks = 0; ks < 2; ++ks) {
      v8s af[2], bf[4];
      for (int rt = 0; rt < 2; ++rt) {
        int ra = wr * 32 + rt * 16 + (lane & 15);
        int ca = (ks * 4 + (lane >> 4)) ^ (ra & 7);
        af[rt] = *(const v8s*)&As[ra * 64 + ca * 8];
      }
      for (int ct = 0; ct < 4; ++ct) {
        int rb = wc * 64 + ct * 16 + (lane & 15);
        int cb = (ks * 4 + (lane >> 4)) ^ (rb & 7);
        bf[ct] = *(const v8s*)&Bs[rb * 64 + cb * 8];
      }
      for (int rt = 0; rt < 2; ++rt)
        for (int ct = 0; ct < 4; ++ct)
          acc[rt][ct] = mfma16(af[rt], bf[ct], acc[rt][ct]);
    }
  };

  STAGE(0, 0);
  __syncthreads();
  for (int kt = 0; kt < 15; ++kt) {
    STAGE((kt + 1) & 1, (kt + 1) * 64);
    COMPUTE(kt & 1);
    __syncthreads();
  }
  COMPUTE(1);
  __syncthreads();

  if (bn < 16) {
    float qs = (bn < 8) ? 0.0450842200f : 1.0f;     // log2(e)/32 folded into Q
    for (int ct = 0; ct < 4; ++ct) {
      int col = wc * 64 + ct * 16 + (lane & 15);
      for (int rt = 0; rt < 2; ++rt)
        for (int j = 0; j < 4; ++j) {
          int m = wr * 32 + rt * 16 + ((lane >> 4) << 2) + j;
          S[m * 128 + (((col >> 3) ^ (m & 7)) << 3) + (col & 7)] =
              bf16bits(acc[rt][ct][j] * qs);
        }
    }
    __syncthreads();
    for (int i = 0; i < 4; ++i) {
      int c = i * 256 + tid;
      int m = c >> 4, c8 = c & 15;
      v8s v = *(const v8s*)&S[m * 128 + ((c8 ^ (m & 7)) << 3)];
      *(v8s*)&Cq[(size_t)(bm * 64 + m) * 2048 + bn * 128 + c8 * 8] = v;
    }
  } else {
    for (int ct = 0; ct < 4; ++ct) {
      int n = wc * 64 + ct * 16 + (lane & 15);
      for (int rt = 0; rt < 2; ++rt) {
        int m0 = wr * 32 + rt * 16 + ((lane >> 4) << 2);
        ushort4 p4;
        p4.x = bf16bits(acc[rt][ct][0]); p4.y = bf16bits(acc[rt][ct][1]);
        p4.z = bf16bits(acc[rt][ct][2]); p4.w = bf16bits(acc[rt][ct][3]);
        *(ushort4*)&S[n * 64 + (((m0 >> 3) ^ (n & 7)) << 3) + (m0 & 7)] = p4;
      }
    }
    __syncthreads();
    int b = bm >> 5, s0 = (bm & 31) * 64;
    for (int i = 0; i < 4; ++i) {
      int c = i * 256 + tid;
      int n = c >> 3, c8 = c & 7;
      v8s v = *(const v8s*)&S[n * 64 + ((c8 ^ (n & 7)) << 3)];
      int nn = bn * 128 + n - 2048;
      int head = nn >> 6, d = nn & 63;
      *(v8s*)&VTh[(size_t)((b * 16 + head) * 64 + d) * 2048 + s0 + c8 * 8] = v;
    }
  }
}

// ---------------- attention: QBLK=64, 4 waves = 2 q-halves x 2 key-parities ----------------
// wave w: qhalf=w&1 (32 q-rows), kpar=w>>1 (k-tiles 2t+kpar). Per-tile body =
// verified r11 (swapped mfma32 + in-register softmax). Partial O/rsum combined
// across parity waves via LDS (exp partials additive; single normalize).
__global__ __launch_bounds__(256) void attn_kernel(const unsigned short* __restrict__ Cq,
                                                   const unsigned short* __restrict__ VTh,
                                                   float* __restrict__ out) {
  __shared__ __align__(16) unsigned short Qs[64 * 64];      // 8KB
  __shared__ __align__(16) unsigned short Ks[2][64 * 64];   // 16KB (par 0/1)
  __shared__ __align__(16) unsigned short Vs[2][64 * 64];   // 16KB
  int tid = threadIdx.x, lane = tid & 63, wave = tid >> 6;
  int ln31 = lane & 31, h = lane >> 5;
  int qhalf = wave & 1, kpar = wave >> 1;
  int flat = blockIdx.x + (blockIdx.y << 5);               // grid (32,32) -> 0..1023
  int swz = (flat & 7) * 128 + (flat >> 3);                // XCD x: bh in [4x,4x+4)
  int qb = swz & 31, bh = swz >> 5;
  int b = bh >> 4, hH = bh & 15;

  const unsigned short* Qg = Cq + (size_t)(b * 2048 + qb * 64) * 2048 + hH * 64;
  const unsigned short* Kg = Cq + (size_t)(b * 2048) * 2048 + 1024 + hH * 64;
  const unsigned short* Vg = VTh + (size_t)bh * 64 * 2048;

  for (int i = 0; i < 2; ++i) {                  // Q tile 64x64 (swizzled fill)
    int e = i * 256 + tid;
    int row = e >> 3, cc = e & 7;
    int sc = cc ^ (row & 7);
    GLD16(Qg + (size_t)row * 2048 + sc * 8, (char*)Qs + (i * 256 + wave * 64) * 16);
  }
  __syncthreads();

  v8s qf[4];                                     // Q row q=qhalf*32+ln31
#pragma unroll
  for (int ks = 0; ks < 4; ++ks) {
    int rq = qhalf * 32 + ln31;
    int cq = (ks * 2 + h) ^ (rq & 7);
    qf[ks] = *(const v8s*)&Qs[rq * 64 + cq * 8];
  }

  f32x16 acc0 = zero16(), acc1 = zero16();
  float rsum = 0.f;

  for (int t = 0; t < 16; ++t) {
    __syncthreads();                             // prior reads of both buffers done
    for (int i = 0; i < 2; ++i) {                // stage tiles 2t and 2t+1
      int e = i * 256 + tid;
      int row = e >> 3, cc = e & 7;
      int sc = cc ^ (row & 7);
      GLD16(Kg + (size_t)((2 * t) * 64 + row) * 2048 + sc * 8,
            (char*)Ks[0] + (i * 256 + wave * 64) * 16);
      GLD16(Kg + (size_t)((2 * t + 1) * 64 + row) * 2048 + sc * 8,
            (char*)Ks[1] + (i * 256 + wave * 64) * 16);
      GLD16(Vg + row * 2048 + (2 * t) * 64 + sc * 8,
            (char*)Vs[0] + (i * 256 + wave * 64) * 16);
      GLD16(Vg + row * 2048 + (2 * t + 1) * 64 + sc * 8,
            (char*)Vs[1] + (i * 256 + wave * 64) * 16);
    }
    __syncthreads();                             // tiles landed

    const unsigned short* Ksp = Ks[kpar];
    const unsigned short* Vsp = Vs[kpar];

    // S^T = mfma32(K, Q)
    f32x16 s0 = zero16(), s1 = zero16();
#pragma unroll
    for (int ks = 0; ks < 4; ++ks) {
      int ck = (ks * 2 + h) ^ (ln31 & 7);
      v8s kf0 = *(const v8s*)&Ksp[ln31 * 64 + ck * 8];
      v8s kf1 = *(const v8s*)&Ksp[(32 + ln31) * 64 + ck * 8];
      s0 = mfma32(kf0, qf[ks], s0);
      s1 = mfma32(kf1, qf[ks], s1);
    }

    // exp2, pack, permlane-redistribute, PV (verified r11 body)
#pragma unroll
    for (int mt = 0; mt < 2; ++mt) {
      const f32x16 st = mt ? s1 : s0;
      float p[16];
#pragma unroll
      for (int r = 0; r < 16; ++r) { p[r] = __builtin_amdgcn_exp2f(st[r]); rsum += p[r]; }
      unsigned int w0 = cvtpk(p[0], p[1]),  w1 = cvtpk(p[2], p[3]);
      unsigned int w2 = cvtpk(p[4], p[5]),  w3 = cvtpk(p[6], p[7]);
      unsigned int w4 = cvtpk(p[8], p[9]),  w5 = cvtpk(p[10], p[11]);
      unsigned int w6 = cvtpk(p[12], p[13]), w7 = cvtpk(p[14], p[15]);
      pl32swap(w0, w2); pl32swap(w1, w3);
      pl32swap(w4, w6); pl32swap(w5, w7);
      union { unsigned int u[4]; v8s v; } pa0, pa1;
      pa0.u[0] = w0; pa0.u[1] = w1; pa0.u[2] = w2; pa0.u[3] = w3;
      pa1.u[0] = w4; pa1.u[1] = w5; pa1.u[2] = w6; pa1.u[3] = w7;
#pragma unroll
      for (int s = 0; s < 2; ++s) {
        v8s pa = s ? pa1.v : pa0.v;
        int cb = mt * 4 + s * 2 + h;
        int rv0 = ln31, rv1 = 32 + ln31;
        v8s vb0 = *(const v8s*)&Vsp[rv0 * 64 + ((cb ^ (rv0 & 7))) * 8];
        v8s vb1 = *(const v8s*)&Vsp[rv1 * 64 + ((cb ^ (rv1 & 7))) * 8];
        acc0 = mfma32(pa, vb0, acc0);
        acc1 = mfma32(pa, vb1, acc1);
      }
    }
  }

  // ---- combine parity partials (waves 2,3 -> waves 0,1), normalize, store ----
  __syncthreads();                               // all compute done; LDS reusable
  float* accx = (float*)&Ks[0][0];               // [region r][j 0..31][lane] = 16KB
  float* rsx = (float*)&Vs[0][0];                // [region r][lane]
  if (kpar == 1) {
    int r = qhalf;
#pragma unroll
    for (int j = 0; j < 16; ++j) {
      accx[r * 2048 + j * 64 + lane] = acc0[j];
      accx[r * 2048 + (16 + j) * 64 + lane] = acc1[j];
    }
    rsx[r * 64 + lane] = rsum;
  }
  __syncthreads();
  if (kpar == 0) {
    int r = qhalf;
#pragma unroll
    for (int j = 0; j < 16; ++j) {
      acc0[j] += accx[r * 2048 + j * 64 + lane];
      acc1[j] += accx[r * 2048 + (16 + j) * 64 + lane];
    }
    rsum += rsx[r * 64 + lane];

    float rtot = rsum + __shfl_xor(rsum, 32, 64);
    float inv = 1.0f / rtot;

    int qbase = qb * 64 + qhalf * 32;
#pragma unroll
    for (int r2 = 0; r2 < 16; ++r2) {
      int qr = (r2 & 3) + 8 * (r2 >> 2) + 4 * h;
      float ivr = __shfl(inv, qr, 64);           // inv lives in lane q
      size_t o = (size_t)(b * 2048 + qbase + qr) * 1024 + hH * 64 + ln31;
      out[o] = acc0[r2] * ivr;
      out[o + 32] = acc1[r2] * ivr;
    }
  }
}

extern "C" void kernel_launch(void* const* d_in, const int* in_sizes, int n_in,
                              void* d_out, int out_size, void* d_ws, size_t ws_size,
                              hipStream_t stream) {
  const float* x = (const float*)d_in[0];   // [2,2048,1024]
  const float* w = (const float*)d_in[1];   // [1024,3072]
  float* out = (float*)d_out;

  char* ws = (char*)d_ws;
  unsigned short* xb = (unsigned short*)ws;                  // [4096][1024] bf16, 8 MB
  unsigned short* wT = (unsigned short*)(ws + 8388608);      // [3072][1024] bf16, 6 MB
  unsigned short* Cq = (unsigned short*)(ws + 14680064);     // [4096][2048] bf16 (Q|K)
  unsigned short* VT = (unsigned short*)(ws + 31457280);     // [32][64][2048] bf16

  cvt_x_kernel<<<4096, 256, 0, stream>>>((const float4*)x, (ushort4*)xb, 1048576);
  cvt_wT_kernel<<<dim3(96, 32), 256, 0, stream>>>(w, wT);
  qkv_gemm<<<dim3(64, 24), 256, 0, stream>>>(xb, wT, Cq, VT);
  attn_kernel<<<dim3(32, 32), 256, 0, stream>>>(Cq, VT, out);
}